// Round 9
// baseline (124.226 us; speedup 1.0000x reference)
//
#include <hip/hip_runtime.h>
#include <hip/hip_bf16.h>

// DirectionalSeparableConv2D — round 9.
// r8 = 123us (two-phase: dwconv + MFMA mix, both < 84us, masked in top-5 by
// harness ws-fill dispatches). Floor for this structure ~75-80us.
// This round:
//   k1 dwconv: zero only the halo (152 quads vs 728) and drop to ONE barrier
//              (halo-zero and interior-stage write disjoint LDS).
//   k2 mix:    TILE 64 -> 96 pixels (24 tiles/img, 3072 blocks): A-frags,
//              barrier, launch amortized 1.5x; acc 2x6x4=48 f32, ~110 live
//              regs (no spill risk), LDS 26.1 KB.

namespace {
constexpr int HH = 48, WW = 48;
constexpr int CEN_OUT = 32, DIR_OUT = 24;
constexpr int C_IN = 128, C_OUT = 128, HW = HH * WW;   // 2304
constexpr int NB = 128;
constexpr size_t Y_ELEMS = (size_t)NB * C_IN * HW;
constexpr size_t Y_BYTES = Y_ELEMS * 2;                 // bf16
constexpr size_t M_BYTES = 128 * 128 * 2;               // bf16
constexpr int TILE = 96;                                // pixels per mix tile
constexpr int TPI = HW / TILE;                          // 24
constexpr int PF = TILE / 16;                           // 6 p-frags
}

typedef __attribute__((ext_vector_type(8))) short bf16x8;
typedef __attribute__((ext_vector_type(4))) float f32x4;

__device__ __forceinline__ ushort f2bf(float f) {
    __hip_bfloat16 h = __float2bfloat16(f);
    return *reinterpret_cast<ushort*>(&h);
}

// ======================= k0: build M_bf[o][c] (bf16) =======================
__global__ void build_M(const float* __restrict__ c2c, const float* __restrict__ p2c,
                        const float* __restrict__ d2c, const float* __restrict__ c2d,
                        const float* __restrict__ d2dW, ushort* __restrict__ Mbf) {
    int t = blockIdx.x * 256 + threadIdx.x;
    if (t >= 128 * 128) return;
    int o = t & 127, c = t >> 7;
    float v;
    if (o < 32) {
        if (c < 32)       v = c2c[o * 32 + c];
        else if (c < 56)  v = p2c[o * 24 + c - 32];
        else if (c < 80)  v = p2c[o * 24 + c - 56];
        else if (c < 104) v = d2c[o * 24 + c - 80];
        else              v = d2c[o * 24 + c - 104];
    } else {
        int g = (o - 32) / 24, oo = (o - 32) % 24;
        if (c < 32) v = c2d[oo * 32 + c];
        else {
            int gc = (c - 32) / 24, cc = (c - 32) % 24;
            v = (gc == g) ? d2dW[oo * 24 + cc] : 0.f;
        }
    }
    Mbf[o * 128 + c] = f2bf(v);
}

// ======================= k1: depthwise conv -> y (bf16) =======================
// Block per (b,c) plane; 576 threads. Plane in LDS, zero halo, ONE barrier.
namespace dw {
constexpr int PR = 56;            // padded row stride (floats)
constexpr int NROW = 52;          // rows -2..49
}

__global__ __launch_bounds__(576) void dsc_dwconv(
    const float* __restrict__ x,
    const float* __restrict__ cen_t,   // [32,3,3]
    const float* __restrict__ dir_t,   // [24,5]
    ushort* __restrict__ y)            // bf16 [b*128+c][2304]
{
    __shared__ float xp[dw::NROW * dw::PR];   // 11648 B

    const int bid = blockIdx.x;        // b*128 + c
    const int c   = bid & 127;
    const int tid = threadIdx.x;

    // ---- zero HALO only: rows 0,1,50,51 full width (56 quads) + side strips
    // cols 0..3 & 52..55 of rows 2..49 (96 quads) = 152 quads total.
    {
        float4 z = {0.f, 0.f, 0.f, 0.f};
        if (tid < 152) {
            int qi;
            if (tid < 28) {            // rows 0,1
                int r = tid / 14, q = tid % 14;
                qi = r * 14 + q;
            } else if (tid < 56) {     // rows 50,51
                int t2 = tid - 28;
                int r = 50 + t2 / 14, q = t2 % 14;
                qi = r * 14 + q;
            } else {                   // side strips rows 2..49
                int t2 = tid - 56;
                int r = 2 + (t2 >> 1);
                int q = (t2 & 1) ? 13 : 0;
                qi = r * 14 + q;
            }
            ((float4*)xp)[qi] = z;
        }
    }
    // ---- stage interior (disjoint from halo): rows 2..49, cols 4..51
    {
        const int r = tid / 12, q = tid % 12;
        float4 v = *(const float4*)(x + (size_t)bid * HW + tid * 4);
        *(float4*)&xp[(r + 2) * dw::PR + 4 + q * 4] = v;
    }
    __syncthreads();

    const int row = tid / 12;
    const int w0  = (tid % 12) * 4;
    float o0 = 0.f, o1 = 0.f, o2 = 0.f, o3 = 0.f;

#define XP(r_, c_) xp[(r_) * dw::PR + (c_)]

    if (c < 32) {                      // 3x3: x[h+i-1][w+j-1]
#pragma unroll
        for (int i = 0; i < 3; ++i)
#pragma unroll
            for (int j = 0; j < 3; ++j) {
                float k = cen_t[c * 9 + i * 3 + j];
                int r = row + i + 1, cc = w0 + j + 3;
                o0 += k * XP(r, cc + 0);
                o1 += k * XP(r, cc + 1);
                o2 += k * XP(r, cc + 2);
                o3 += k * XP(r, cc + 3);
            }
    } else if (c < 56) {               // h: x[h][w+i-2]
        int cd = c - 32;
#pragma unroll
        for (int i = 0; i < 5; ++i) {
            float t = dir_t[cd * 5 + i];
            int cc = w0 + i + 2;
            o0 += t * XP(row + 2, cc + 0);
            o1 += t * XP(row + 2, cc + 1);
            o2 += t * XP(row + 2, cc + 2);
            o3 += t * XP(row + 2, cc + 3);
        }
    } else if (c < 80) {               // v: x[h+i-2][w]
        int cd = c - 56;
#pragma unroll
        for (int i = 0; i < 5; ++i) {
            float t = dir_t[cd * 5 + i];
            float4 vq = *(const float4*)&XP(row + i, w0 + 4);
            o0 += t * vq.x; o1 += t * vq.y; o2 += t * vq.z; o3 += t * vq.w;
        }
    } else if (c < 104) {              // d1: x[h+i-2][w+i-2]
        int cd = c - 80;
#pragma unroll
        for (int i = 0; i < 5; ++i) {
            float t = dir_t[cd * 5 + i];
            int cc = w0 + i + 2;
            o0 += t * XP(row + i, cc + 0);
            o1 += t * XP(row + i, cc + 1);
            o2 += t * XP(row + i, cc + 2);
            o3 += t * XP(row + i, cc + 3);
        }
    } else {                           // d2: x[h+i-2][w+2-i]
        int cd = c - 104;
#pragma unroll
        for (int i = 0; i < 5; ++i) {
            float t = dir_t[cd * 5 + i];
            int cc = w0 + 6 - i;
            o0 += t * XP(row + i, cc + 0);
            o1 += t * XP(row + i, cc + 1);
            o2 += t * XP(row + i, cc + 2);
            o3 += t * XP(row + i, cc + 3);
        }
    }
#undef XP

    ushort4 s = {f2bf(o0), f2bf(o1), f2bf(o2), f2bf(o3)};
    *(ushort4*)&y[(size_t)bid * HW + row * WW + w0] = s;
}

// ======================= k2: MFMA pointwise mix (TILE=96) =======================
// out[o, 96p] = M[o,c] @ y[c, 96p] per tile. 4 waves x 32 out-ch.
// A-frag (M): lane holds M[o0+(l&15)][kb*32+(l>>4)*8 + 0..7]  (global, L2-hot)
// B-frag (y): yT[pf*16+(l&15)][kb*32+(l>>4)*8 + 0..7] (ds_read_b128)
// D: col = lane&15 = pixel, row = (lane>>4)*4+r = out-ch.
__global__ __launch_bounds__(256) void dsc_mix(
    const ushort* __restrict__ y,      // bf16 [b*128+c][2304]
    const ushort* __restrict__ Mbf,    // bf16 [128o][128c]
    float* __restrict__ out)
{
    __shared__ ushort yT[TILE][136];   // 26112 B

    const int tid = threadIdx.x;
    const int b   = blockIdx.x / TPI;
    const int p0  = (blockIdx.x % TPI) * TILE;
    const int l   = tid & 63;
    const int wv  = tid >> 6;          // 0..3 -> out-ch [wv*32, wv*32+32)

    // ---- A-frags from global ----
    bf16x8 afr[2][4];
#pragma unroll
    for (int of = 0; of < 2; ++of)
#pragma unroll
        for (int kb = 0; kb < 4; ++kb) {
            int ro = wv * 32 + of * 16 + (l & 15);
            int co = kb * 32 + (l >> 4) * 8;
            afr[of][kb] = *(const bf16x8*)(Mbf + ro * 128 + co);
        }

    // ---- stage y tile transposed: yT[p][c], 96p x 128c ----
    {
        const int c = tid & 127;
        const ushort* src = y + (size_t)b * C_IN * HW + (size_t)c * HW + p0;
#pragma unroll
        for (int k = 0; k < 6; ++k) {
            int oct = (tid >> 7) + k * 2;          // 0..11
            uint4 v = *(const uint4*)(src + oct * 8);
            const ushort* pv = (const ushort*)&v;
#pragma unroll
            for (int i = 0; i < 8; ++i)
                yT[oct * 8 + i][c] = pv[i];
        }
    }
    __syncthreads();

    // ---- MFMA: 2 o-frags x 6 p-frags x 4 K-steps ----
    f32x4 acc[2][PF] = {};
#pragma unroll
    for (int kb = 0; kb < 4; ++kb)
#pragma unroll
        for (int pf = 0; pf < PF; ++pf) {
            bf16x8 bfr = *(const bf16x8*)&yT[pf * 16 + (l & 15)][kb * 32 + (l >> 4) * 8];
            acc[0][pf] = __builtin_amdgcn_mfma_f32_16x16x32_bf16(afr[0][kb], bfr, acc[0][pf], 0, 0, 0);
            acc[1][pf] = __builtin_amdgcn_mfma_f32_16x16x32_bf16(afr[1][kb], bfr, acc[1][pf], 0, 0, 0);
        }

    // ---- store ----
    float* __restrict__ ob = out + (size_t)b * C_OUT * HW;
#pragma unroll
    for (int of = 0; of < 2; ++of)
#pragma unroll
        for (int pf = 0; pf < PF; ++pf) {
            int o_base = wv * 32 + of * 16 + (l >> 4) * 4;
            int p = p0 + pf * 16 + (l & 15);
#pragma unroll
            for (int r = 0; r < 4; ++r)
                ob[(size_t)(o_base + r) * HW + p] = acc[of][pf][r];
        }
}

// ======================= fallback (r6 kernel, ws too small) =======================
namespace fb {
constexpr int TH = 8, RH = 12, RW = 64, QPR = 16, NT = 384;

__device__ __forceinline__ void gl_lds16(const float* g, float* l) {
    __builtin_amdgcn_global_load_lds(
        (const __attribute__((address_space(1))) unsigned int*)g,
        (__attribute__((address_space(3))) unsigned int*)l, 16, 0, 0);
}
template <int C>
__device__ __forceinline__ void stage(float* __restrict__ xsf,
                                      const float* __restrict__ xb,
                                      const float* __restrict__ zb,
                                      int c0, int h0, int tid) {
    constexpr int ITEMS = C * RH * QPR;
    constexpr int PT = ITEMS / NT;
#pragma unroll
    for (int k = 0; k < PT; ++k) {
        int i = tid + k * NT;
        int q = i & (QPR - 1);
        int rc = i >> 4;
        int r = rc % RH;
        int c = rc / RH;
        int gh = h0 - 2 + r;
        bool ok = ((unsigned)gh < (unsigned)HH) && (q < 12);
        const float* src = ok ? (xb + (size_t)(c0 + c) * HW + gh * WW + q * 4) : zb;
        gl_lds16(src, xsf + (size_t)i * 4);
    }
}

#define CONV3(N, CB)                                                          \
    do {                                                                      \
        _Pragma("unroll") for (int c = 0; c < (N); ++c) {                     \
            float a = 0.f;                                                    \
            _Pragma("unroll") for (int i = 0; i < 3; ++i)                     \
                _Pragma("unroll") for (int j = 0; j < 3; ++j)                 \
                    a += cen_t[((CB) + c) * 9 + i * 3 + j] *                  \
                         xs[c][hl + 1 + i][woff[j + 1]];                      \
            y[c] = a;                                                         \
        }                                                                     \
    } while (0)
#define CONVDIR(CB, ROW, COL)                                                 \
    do {                                                                      \
        _Pragma("unroll") for (int c = 0; c < 12; ++c) {                      \
            float a = 0.f;                                                    \
            _Pragma("unroll") for (int i = 0; i < 5; ++i)                     \
                a += dir_t[((CB) + c) * 5 + i] * xs[c][ROW][COL];             \
            y[c] = a;                                                         \
        }                                                                     \
    } while (0)
#define FOLD_CEN(CB, N)                                                       \
    do {                                                                      \
        _Pragma("unroll") for (int o = 0; o < CEN_OUT; ++o) {                 \
            float a = cen_acc[o];                                             \
            _Pragma("unroll") for (int c = 0; c < (N); ++c)                   \
                a += c2c[o * 32 + (CB) + c] * y[c];                           \
            cen_acc[o] = a;                                                   \
        }                                                                     \
        _Pragma("unroll") for (int o = 0; o < DIR_OUT; ++o) {                 \
            float a = od[o];                                                  \
            _Pragma("unroll") for (int c = 0; c < (N); ++c)                   \
                a += c2d[o * 32 + (CB) + c] * y[c];                           \
            od[o] = a;                                                        \
        }                                                                     \
    } while (0)
#define FOLD_DIR0(W2C)                                                        \
    do {                                                                      \
        _Pragma("unroll") for (int o = 0; o < CEN_OUT; ++o) {                 \
            float a = cen_acc[o];                                             \
            _Pragma("unroll") for (int c = 0; c < 12; ++c)                    \
                a += (W2C)[o * 24 + c] * y[c];                                \
            cen_acc[o] = a;                                                   \
        }                                                                     \
        _Pragma("unroll") for (int o = 0; o < DIR_OUT; ++o) {                 \
            float a = odl[o][tid];                                            \
            _Pragma("unroll") for (int c = 0; c < 12; ++c)                    \
                a += d2dW[o * 24 + c] * y[c];                                 \
            da[o] = a;                                                        \
        }                                                                     \
    } while (0)
#define FOLD_DIR1(W2C, G)                                                     \
    do {                                                                      \
        _Pragma("unroll") for (int o = 0; o < CEN_OUT; ++o) {                 \
            float a = cen_acc[o];                                             \
            _Pragma("unroll") for (int c = 0; c < 12; ++c)                    \
                a += (W2C)[o * 24 + 12 + c] * y[c];                           \
            cen_acc[o] = a;                                                   \
        }                                                                     \
        _Pragma("unroll") for (int o = 0; o < DIR_OUT; ++o) {                 \
            float a = da[o];                                                  \
            _Pragma("unroll") for (int c = 0; c < 12; ++c)                    \
                a += d2dW[o * 24 + 12 + c] * y[c];                            \
            ob[(size_t)(CEN_OUT + (G) * DIR_OUT + o) * HW + pix] = a;         \
        }                                                                     \
    } while (0)

__global__ __launch_bounds__(NT) void dsc6(
    const float* __restrict__ x, const float* __restrict__ cen_t,
    const float* __restrict__ dir_t, const float* __restrict__ c2c,
    const float* __restrict__ p2c, const float* __restrict__ d2c,
    const float* __restrict__ c2d, const float* __restrict__ d2dW,
    const float* __restrict__ zb, float* __restrict__ out)
{
    __shared__ float xs[12][RH][RW];
    __shared__ float odl[DIR_OUT][NT];
    float* xsf = &xs[0][0][0];
    const int tid = threadIdx.x;
    const int w  = tid % WW;
    const int hl = tid / WW;
    const int b  = blockIdx.x / (HH / TH);
    const int h0 = (blockIdx.x % (HH / TH)) * TH;
    const int h  = h0 + hl;
    const float* __restrict__ xb = x   + (size_t)b * C_IN  * HW;
    float* __restrict__       ob = out + (size_t)b * C_OUT * HW;
    const int pix = h * WW + w;
    int woff[5];
#pragma unroll
    for (int i = 0; i < 5; ++i) {
        int ww2 = w + i - 2;
        woff[i] = ((unsigned)ww2 < (unsigned)WW) ? ww2 : 48;
    }
    float cen_acc[CEN_OUT], od[DIR_OUT], da[DIR_OUT], y[12];
#pragma unroll
    for (int o = 0; o < CEN_OUT; ++o) cen_acc[o] = 0.f;
#pragma unroll
    for (int o = 0; o < DIR_OUT; ++o) od[o] = 0.f;

    stage<12>(xsf, xb, zb, 0, h0, tid);
    __syncthreads();
    CONV3(12, 0);
    __syncthreads();
    stage<12>(xsf, xb, zb, 12, h0, tid);
    FOLD_CEN(0, 12);
    __syncthreads();
    CONV3(12, 12);
    __syncthreads();
    stage<8>(xsf, xb, zb, 24, h0, tid);
    FOLD_CEN(12, 12);
    __syncthreads();
    CONV3(8, 24);
    __syncthreads();
    stage<12>(xsf, xb, zb, 32, h0, tid);
    FOLD_CEN(24, 8);
#pragma unroll
    for (int o = 0; o < DIR_OUT; ++o) odl[o][tid] = od[o];
    __syncthreads();
    CONVDIR(0, hl + 2, woff[i]);
    __syncthreads();
    stage<12>(xsf, xb, zb, 44, h0, tid);
    FOLD_DIR0(p2c);
    __syncthreads();
    CONVDIR(12, hl + 2, woff[i]);
    __syncthreads();
    stage<12>(xsf, xb, zb, 56, h0, tid);
    FOLD_DIR1(p2c, 0);
    __syncthreads();
    CONVDIR(0, hl + i, w);
    __syncthreads();
    stage<12>(xsf, xb, zb, 68, h0, tid);
    FOLD_DIR0(p2c);
    __syncthreads();
    CONVDIR(12, hl + i, w);
    __syncthreads();
    stage<12>(xsf, xb, zb, 80, h0, tid);
    FOLD_DIR1(p2c, 1);
    __syncthreads();
    CONVDIR(0, hl + i, woff[i]);
    __syncthreads();
    stage<12>(xsf, xb, zb, 92, h0, tid);
    FOLD_DIR0(d2c);
    __syncthreads();
    CONVDIR(12, hl + i, woff[i]);
    __syncthreads();
    stage<12>(xsf, xb, zb, 104, h0, tid);
    FOLD_DIR1(d2c, 2);
    __syncthreads();
    CONVDIR(0, hl + i, woff[4 - i]);
    __syncthreads();
    stage<12>(xsf, xb, zb, 116, h0, tid);
    FOLD_DIR0(d2c);
    __syncthreads();
    CONVDIR(12, hl + i, woff[4 - i]);
    FOLD_DIR1(d2c, 3);
#pragma unroll
    for (int o = 0; o < CEN_OUT; ++o) ob[(size_t)o * HW + pix] = cen_acc[o];
}
}  // namespace fb

// ======================= launcher =======================
extern "C" void kernel_launch(void* const* d_in, const int* in_sizes, int n_in,
                              void* d_out, int out_size, void* d_ws, size_t ws_size,
                              hipStream_t stream) {
    const float* x     = (const float*)d_in[0];
    const float* cen_t = (const float*)d_in[1];
    const float* dir_t = (const float*)d_in[2];
    const float* c2c   = (const float*)d_in[3];
    const float* p2c   = (const float*)d_in[4];
    const float* d2c   = (const float*)d_in[5];
    const float* c2d   = (const float*)d_in[6];
    const float* d2dW  = (const float*)d_in[7];
    float* out = (float*)d_out;

    if (ws_size >= Y_BYTES + M_BYTES) {
        ushort* y   = (ushort*)d_ws;
        ushort* Mbf = (ushort*)((char*)d_ws + Y_BYTES);

        build_M<<<64, 256, 0, stream>>>(c2c, p2c, d2c, c2d, d2dW, Mbf);
        dsc_dwconv<<<NB * C_IN, 576, 0, stream>>>(x, cen_t, dir_t, y);
        dsc_mix<<<NB * TPI, 256, 0, stream>>>(y, Mbf, out);
    } else {
        float* zb = (float*)d_ws;
        hipMemsetAsync(zb, 0, 64, stream);
        fb::dsc6<<<NB * (HH / fb::TH), fb::NT, 0, stream>>>(
            x, cen_t, dir_t, c2c, p2c, d2c, c2d, d2dW, zb, out);
    }
}

// Round 10
// 103.185 us; speedup vs baseline: 1.2039x; 1.2039x over previous
//
#include <hip/hip_runtime.h>
#include <hip/hip_bf16.h>

// DirectionalSeparableConv2D — round 10: single fused kernel.
// r7-r9 two-phase = 123us, floor ~78us (y round-trip 151 MB + 3 launches).
// Fusion: block = (b, 8-row stripe) x 512 thr. Stream x in 8x16-ch chunks
// (global_load_lds, zb row-halo, zero cols 48..63 -> maskless taps via &63),
// dwconv -> ycp[c][p] bf16 (contiguous writes), transpose -> yT[p][c] with
// XOR row swizzle (kills the 32-way conflict of 256B-stride rows), then two
// 64-out-ch MFMA passes (acc 48 f32/thread -> no spills). y never hits HBM.
// LDS 159744 B (1 block/CU). Traffic ~310-380 MB -> ~55us floor.

namespace {
constexpr int HH = 48, WW = 48, HW = HH * WW;
constexpr int C_IN = 128, C_OUT = 128, NB = 128;
constexpr int RPB = 8;                  // stripe rows per block
constexpr int NSTR = HH / RPB;          // 6
constexpr int PIX = RPB * WW;           // 384
constexpr int NT = 512;
constexpr int CHK = 16;                 // channels per chunk
constexpr int NCHK = C_IN / CHK;        // 8
constexpr int XR = RPB + 4;             // 12 staged rows
constexpr int XW = 64;                  // staged row stride (floats)
constexpr size_t M_BYTES = 128 * 128 * 2;
constexpr size_t ZB_OFF = M_BYTES;      // zb after Mbf in ws
}

typedef __attribute__((ext_vector_type(8))) short bf16x8;
typedef __attribute__((ext_vector_type(4))) float f32x4;

__device__ __forceinline__ ushort f2bf(float f) {
    __hip_bfloat16 h = __float2bfloat16(f);
    return *reinterpret_cast<ushort*>(&h);
}

// ======================= k0: build M_bf[o][c] (bf16) =======================
__global__ void build_M(const float* __restrict__ c2c, const float* __restrict__ p2c,
                        const float* __restrict__ d2c, const float* __restrict__ c2d,
                        const float* __restrict__ d2dW, ushort* __restrict__ Mbf) {
    int t = blockIdx.x * 256 + threadIdx.x;
    if (t >= 128 * 128) return;
    int o = t & 127, c = t >> 7;
    float v;
    if (o < 32) {
        if (c < 32)       v = c2c[o * 32 + c];
        else if (c < 56)  v = p2c[o * 24 + c - 32];
        else if (c < 80)  v = p2c[o * 24 + c - 56];
        else if (c < 104) v = d2c[o * 24 + c - 80];
        else              v = d2c[o * 24 + c - 104];
    } else {
        int g = (o - 32) / 24, oo = (o - 32) % 24;
        if (c < 32) v = c2d[oo * 32 + c];
        else {
            int gc = (c - 32) / 24, cc2 = (c - 32) % 24;
            v = (gc == g) ? d2dW[oo * 24 + cc2] : 0.f;
        }
    }
    Mbf[o * 128 + c] = f2bf(v);
}

// ======================= fused kernel =======================
__global__ __launch_bounds__(NT) void dsc_fused(
    const float* __restrict__ x,
    const float* __restrict__ cen_t,   // [32,3,3]
    const float* __restrict__ dir_t,   // [24,5]
    const ushort* __restrict__ Mbf,    // bf16 [128o][128c]
    const float* __restrict__ zb,      // 16B zero block
    float* __restrict__ out)
{
    __shared__ float  xs[CHK][XR][XW];     // 49152 B; cols 48..63 = zeros (zb)
    __shared__ ushort yT[PIX * 128];       // 98304 B; row-XOR-swizzled [p][c]
    __shared__ ushort ycp[CHK][PIX];       // 12288 B; per-chunk [c][p]

    const int tid = threadIdx.x;
    const int b   = blockIdx.x / NSTR;
    const int h0  = (blockIdx.x % NSTR) * RPB;
    const float* __restrict__ xb = x + (size_t)b * C_IN * HW;

    // ---- stage chunk t: 16ch x 12 rows x 16 quads, linear LDS dest ----
    auto stage = [&](int t) {
        const int c0 = t * CHK;
#pragma unroll
        for (int k = 0; k < 6; ++k) {          // 3072 quads / 512 thr
            int i  = tid + k * NT;
            int q  = i & 15;
            int rc = i >> 4;
            int r  = rc % XR;
            int c  = rc / XR;
            int gh = h0 - 2 + r;
            bool ok = ((unsigned)gh < (unsigned)HH) && (q < 12);
            const float* src = ok ? (xb + (size_t)(c0 + c) * HW + gh * WW + q * 4) : zb;
            __builtin_amdgcn_global_load_lds(
                (const __attribute__((address_space(1))) unsigned int*)src,
                (__attribute__((address_space(3))) unsigned int*)(&xs[0][0][0] + (size_t)i * 4),
                16, 0, 0);
        }
    };

    // ---- dwconv chunk t: tasks (c,row,quad) -> 4 y values -> ycp[c][p] ----
    auto dwconv = [&](int t) {
        const int c0 = t * CHK;
#pragma unroll
        for (int k = 0; k < 3; ++k) {          // 1536 tasks / 512 thr
            int task = tid + k * NT;
            int c    = task / 96;
            int rem  = task % 96;
            int row  = rem / 12;
            int w0   = (rem % 12) * 4;
            int cc   = c0 + c;
            float o0 = 0.f, o1 = 0.f, o2 = 0.f, o3 = 0.f;
            if (cc < 32) {                      // 3x3
#pragma unroll
                for (int i = 0; i < 3; ++i) {
                    float v[6];
#pragma unroll
                    for (int j = 0; j < 6; ++j) v[j] = xs[c][row + 1 + i][(w0 + j - 1) & 63];
                    float k0 = cen_t[cc * 9 + i * 3 + 0];
                    float k1 = cen_t[cc * 9 + i * 3 + 1];
                    float k2 = cen_t[cc * 9 + i * 3 + 2];
                    o0 += k0 * v[0] + k1 * v[1] + k2 * v[2];
                    o1 += k0 * v[1] + k1 * v[2] + k2 * v[3];
                    o2 += k0 * v[2] + k1 * v[3] + k2 * v[4];
                    o3 += k0 * v[3] + k1 * v[4] + k2 * v[5];
                }
            } else if (cc < 56) {               // horizontal 1x5
                int cd = cc - 32;
                float v[8];
#pragma unroll
                for (int j = 0; j < 8; ++j) v[j] = xs[c][row + 2][(w0 + j - 2) & 63];
#pragma unroll
                for (int i = 0; i < 5; ++i) {
                    float tt = dir_t[cd * 5 + i];
                    o0 += tt * v[i]; o1 += tt * v[i + 1]; o2 += tt * v[i + 2]; o3 += tt * v[i + 3];
                }
            } else if (cc < 80) {               // vertical 5x1
                int cd = cc - 56;
#pragma unroll
                for (int i = 0; i < 5; ++i) {
                    float tt = dir_t[cd * 5 + i];
                    float4 vq = *(const float4*)&xs[c][row + i][w0];
                    o0 += tt * vq.x; o1 += tt * vq.y; o2 += tt * vq.z; o3 += tt * vq.w;
                }
            } else if (cc < 104) {              // diag x[h+i-2][w+i-2]
                int cd = cc - 80;
#pragma unroll
                for (int i = 0; i < 5; ++i) {
                    float tt = dir_t[cd * 5 + i];
                    int base = w0 + i - 2;
                    o0 += tt * xs[c][row + i][(base + 0) & 63];
                    o1 += tt * xs[c][row + i][(base + 1) & 63];
                    o2 += tt * xs[c][row + i][(base + 2) & 63];
                    o3 += tt * xs[c][row + i][(base + 3) & 63];
                }
            } else {                            // anti-diag x[h+i-2][w+2-i]
                int cd = cc - 104;
#pragma unroll
                for (int i = 0; i < 5; ++i) {
                    float tt = dir_t[cd * 5 + i];
                    int base = w0 + 2 - i;
                    o0 += tt * xs[c][row + i][(base + 0) & 63];
                    o1 += tt * xs[c][row + i][(base + 1) & 63];
                    o2 += tt * xs[c][row + i][(base + 2) & 63];
                    o3 += tt * xs[c][row + i][(base + 3) & 63];
                }
            }
            int p = row * 48 + w0;
            ushort4 s = {f2bf(o0), f2bf(o1), f2bf(o2), f2bf(o3)};
            *(ushort4*)&ycp[c][p] = s;          // contiguous 8B write
        }
    };

    // ---- transpose chunk t: ycp[c][p] -> yT[p][c0+c] (XOR-swizzled) ----
    auto transpose = [&](int t) {
        const int c0 = t * CHK;
#pragma unroll
        for (int k = 0; k < 3; ++k) {          // 1536 tasks / 512 thr
            int t2 = tid + k * NT;
            int cq = t2 / PIX;                  // 0..3 (4-ch group)
            int p  = t2 % PIX;
            ushort4 s;
            s.x = ycp[cq * 4 + 0][p];
            s.y = ycp[cq * 4 + 1][p];
            s.z = ycp[cq * 4 + 2][p];
            s.w = ycp[cq * 4 + 3][p];
            int byte = (p << 8) + ((c0 + cq * 4) << 1);
            byte ^= (p & 7) << 4;
            *(ushort4*)((char*)yT + byte) = s;
        }
    };

    // ================= channel-streamed dwconv =================
    stage(0);
    __syncthreads();
    for (int t = 0; t < NCHK; ++t) {
        dwconv(t);
        __syncthreads();                        // xs reads done
        if (t + 1 < NCHK) stage(t + 1);         // async DMA overlaps transpose
        transpose(t);
        __syncthreads();                        // DMA drained + yT/ycp settled
    }

    // ================= MFMA mix: 2 passes x 64 out-ch =================
    const int l     = tid & 63;
    const int wv    = tid >> 6;                 // 0..7
    const int ofr   = wv & 3;                   // o-frag within 64-ch half
    const int phalf = wv >> 2;                  // 0/1 -> p-frags 0..11 / 12..23
    float* __restrict__ ob = out + (size_t)b * C_OUT * HW + h0 * WW;

#pragma unroll
    for (int pass = 0; pass < 2; ++pass) {
        int o0 = pass * 64 + ofr * 16;
        bf16x8 afr[4];
#pragma unroll
        for (int kb = 0; kb < 4; ++kb)
            afr[kb] = *(const bf16x8*)(Mbf + (o0 + (l & 15)) * 128 + kb * 32 + (l >> 4) * 8);
        f32x4 acc[12] = {};
#pragma unroll
        for (int kb = 0; kb < 4; ++kb)
#pragma unroll
            for (int pf = 0; pf < 12; ++pf) {
                int p = (phalf * 12 + pf) * 16 + (l & 15);
                int byte = (p << 8) + ((kb * 32 + (l >> 4) * 8) << 1);
                byte ^= (p & 7) << 4;
                bf16x8 bfr = *(const bf16x8*)((const char*)yT + byte);
                acc[pf] = __builtin_amdgcn_mfma_f32_16x16x32_bf16(afr[kb], bfr, acc[pf], 0, 0, 0);
            }
#pragma unroll
        for (int pf = 0; pf < 12; ++pf) {
            int p = (phalf * 12 + pf) * 16 + (l & 15);
            int obase = o0 + (l >> 4) * 4;
#pragma unroll
            for (int r = 0; r < 4; ++r)
                ob[(size_t)(obase + r) * HW + p] = acc[pf][r];
        }
    }
}

// ======================= launcher =======================
extern "C" void kernel_launch(void* const* d_in, const int* in_sizes, int n_in,
                              void* d_out, int out_size, void* d_ws, size_t ws_size,
                              hipStream_t stream) {
    const float* x     = (const float*)d_in[0];
    const float* cen_t = (const float*)d_in[1];
    const float* dir_t = (const float*)d_in[2];
    const float* c2c   = (const float*)d_in[3];
    const float* p2c   = (const float*)d_in[4];
    const float* d2c   = (const float*)d_in[5];
    const float* c2d   = (const float*)d_in[6];
    const float* d2dW  = (const float*)d_in[7];
    float* out = (float*)d_out;

    ushort* Mbf = (ushort*)d_ws;                       // 32 KiB
    float*  zb  = (float*)((char*)d_ws + ZB_OFF);      // 16 B zero block

    hipMemsetAsync(zb, 0, 64, stream);                 // ws is poisoned each run
    build_M<<<64, 256, 0, stream>>>(c2c, p2c, d2c, c2d, d2dW, Mbf);
    dsc_fused<<<NB * NSTR, NT, 0, stream>>>(x, cen_t, dir_t, Mbf, zb, out);
}